// Round 10
// baseline (188.393 us; speedup 1.0000x reference)
//
#include <hip/hip_runtime.h>
#include <math.h>

// IDMForwardSim R10: dual-recurrence pipe overlap. NB=32 (groups A/B of 16 batches),
// 256 blocks x 448 thr. Per iter: phase1 = MFMA_A || gates_B, barrier,
// phase2 = MFMA_B || gates_A, barrier. MFMA and VALU pipes co-issue (m114), so each
// wave's per-group-step critical path ~ max(MFMA, gates) instead of sum. Single-
// buffered hA/hB (reads and writes are in opposite phases). Same weight frags serve
// both groups. Logit = Wh-pad column 100 (R8); B's final logit read from registers.

#define B_TOT 8192
#define T_STEPS 40

typedef _Float16 f16;
typedef f16 f16x4 __attribute__((ext_vector_type(4)));
typedef f16 f16x8 __attribute__((ext_vector_type(8)));
typedef float f32x4 __attribute__((ext_vector_type(4)));

__device__ __forceinline__ float rcpf(float x) { return __builtin_amdgcn_rcpf(x); }
__device__ __forceinline__ float ex2(float x)  { return __builtin_amdgcn_exp2f(x); }
__device__ __forceinline__ float sigf(float x)  { return rcpf(1.f + ex2(-1.44269504f * x)); }

// ws layout (bytes): whb f16[65536] @0 | wxb f16[65536] @131072 | bp f32[512] @262144

__global__ __launch_bounds__(256) void idm_prep(
    const float* __restrict__ Wx, const float* __restrict__ Wh,
    const float* __restrict__ bvec, const float* __restrict__ attw,
    f16* __restrict__ whb, f16* __restrict__ wxb,
    float* __restrict__ bp)
{
  int i = blockIdx.x * 256 + threadIdx.x;  // i = k*512 + n (coalesced reads)
  int k = i >> 9, n = i & 511;
  int g = n >> 7, j128 = n & 127;
  float vh = 0.f, vx = 0.f;
  if (j128 < 100) {
    int col = g * 100 + j128;
    if (k < 100)      { vh = Wh[k * 400 + col]; vx = Wx[k * 400 + col]; }
    else if (k < 102) { vh = Wx[k * 400 + col]; }  // sdv rows folded into Wh-pad
  } else if (n == 100 && k < 100) {
    vh = attw[k];  // logit row: z^T[100] = h . att_W
  }
  int idx = (((n >> 4) * 4 + (k >> 5)) * 64 + (((k >> 3) & 3) * 16 + (n & 15))) * 8 + (k & 7);
  whb[idx] = (f16)vh;
  wxb[idx] = (f16)vx;
  if (i < 512) { int gg = i >> 7, jj = i & 127; bp[i] = (jj < 100) ? bvec[gg * 100 + jj] : 0.f; }
}

#define GATES(ZS, CST, DEST)                                            \
  {                                                                     \
    f16x4 h4;                                                           \
    _Pragma("unroll")                                                   \
    for (int r = 0; r < 4; ++r) {                                       \
      float ei = ex2(-1.44269504f * ZS[0][r]);                          \
      float sf = sigf(ZS[1][r]);                                        \
      float eg = ex2(-2.88539008f * fmaxf(ZS[2][r], -30.f));            \
      float it = (1.f - eg) * rcpf((1.f + ei) * (1.f + eg));            \
      float cc = fmaf(sf, CST[r], it);                                  \
      float eo = ex2(-1.44269504f * ZS[3][r]);                          \
      float ec = ex2(-2.88539008f * fmaxf(cc, -30.f));                  \
      float hh = (1.f - ec) * rcpf((1.f + eo) * (1.f + ec));            \
      CST[r] = cc;                                                      \
      h4[r] = (f16)hh;                                                  \
    }                                                                   \
    if (hlive) *(f16x4*)(&DEST[lr][j0]) = h4;                           \
  }

__global__ __launch_bounds__(448, 2) void idm_main(
    const float* __restrict__ z_att,
    const float* __restrict__ linear_W,
    const float* __restrict__ linear_b,
    const float* __restrict__ sdv_acts,
    const f16* __restrict__ whb, const f16* __restrict__ wxb,
    const float* __restrict__ bp,
    const float* __restrict__ idm_params,
    const float* __restrict__ idm_s,
    const float* __restrict__ att_b,
    const float* __restrict__ noise_f,
    const float* __restrict__ noise_m,
    float* __restrict__ out)
{
  __shared__ f16   hA[16][136], hB[16][136];  // [batch][k] 0..99 h, 100..101 sdv, pad 0
  __shared__ f16   sdvS[T_STEPS][32][2];
  __shared__ float logitS[T_STEPS][32];       // A: cols 0..15, B: 16..31
  __shared__ float sS[32][T_STEPS][6];        // idm_s fields 1,2,4,5,6,7
  __shared__ float nS[2][T_STEPS][32];
  __shared__ float accS[2][32][T_STEPS];      // act, att

  const int tid = threadIdx.x;
  const int w  = tid >> 6;   // 0..6
  const int l  = tid & 63;
  const int lr = l & 15;     // batch-in-group
  const int lq = l >> 4;
  const int b0g = blockIdx.x * 32;
  const int j0 = 16 * w + lq * 4;
  const bool hlive = (j0 < 100);
  const bool w6log = (w == 6 && lq == 1);
  const bool sduty = (w == 6 && (lq == 1 || lq == 2));

  for (int idx = tid; idx < 1088; idx += 448) {
    ((unsigned*)hA)[idx] = 0u; ((unsigned*)hB)[idx] = 0u;
  }
  // staging (coalesced): sdv 2560f, idm_s fields 10240f, noise 2560f
  for (int idx = tid; idx < 2560; idx += 448) {
    float v = sdv_acts[(size_t)b0g * 80 + idx];
    int b = idx / 80, r = idx - b * 80;
    sdvS[r >> 1][b][r & 1] = (f16)v;
  }
  for (int idx = tid; idx < 10240; idx += 448) {
    int f = idx & 7;
    if (f != 0 && f != 3) {
      int b = idx / 320, rem = idx - b * 320, t = rem >> 3;
      sS[b][t][(f < 3) ? f - 1 : f - 2] = idm_s[(size_t)b0g * 320 + idx];
    }
  }
  for (int idx = tid; idx < 2560; idx += 448) {
    int which = idx >= 1280 ? 1 : 0;
    int r = idx - which * 1280;
    int t = r >> 5, i = r & 31;
    nS[which][t][i] = which ? noise_m[(size_t)t * B_TOT + b0g + i]
                            : noise_f[(size_t)t * B_TOT + b0g + i];
  }
  __syncthreads();

  // h0 = att_proj for both groups; sdv_0
  #pragma unroll
  for (int grp = 0; grp < 2; ++grp) {
    if (tid < 256) {
      int b = tid >> 4, oct = tid & 15;
      float za[10];
      #pragma unroll
      for (int t2 = 0; t2 < 10; ++t2) za[t2] = z_att[(b0g + grp * 16 + b) * 10 + t2];
      #pragma unroll
      for (int jj = 0; jj < 8; ++jj) {
        int j = oct * 8 + jj;
        if (j < 100) {
          float acc = linear_b[j];
          #pragma unroll
          for (int t2 = 0; t2 < 10; ++t2) acc = fmaf(za[t2], linear_W[t2 * 100 + j], acc);
          (grp ? hB : hA)[b][j] = (f16)acc;
        }
      }
    }
  }
  if (tid < 64) {
    int b = tid >> 1, ii = tid & 1;
    (b >= 16 ? hB : hA)[b & 15][100 + ii] = sdvS[0][b][ii];
  }
  __syncthreads();

  // Wx frags -> cxA/cxB, then Wh frags (loop-invariant)
  f16x8 wb[4][4];
  #pragma unroll
  for (int g = 0; g < 4; ++g) {
    int tile = w + 8 * g;
    #pragma unroll
    for (int kf = 0; kf < 4; ++kf)
      wb[g][kf] = *(const f16x8*)(wxb + ((size_t)(tile * 4 + kf) * 64 + l) * 8);
  }
  f32x4 cxA[4], cxB[4];
  #pragma unroll
  for (int g = 0; g < 4; ++g) {
    f32x4 bv = *(const f32x4*)(bp + (w + 8 * g) * 16 + lq * 4);
    cxA[g] = bv; cxB[g] = bv;
  }
  #pragma unroll
  for (int kf = 0; kf < 4; ++kf) {
    f16x8 aA = *(const f16x8*)(&hA[lr][kf * 32 + lq * 8]);
    f16x8 aB = *(const f16x8*)(&hB[lr][kf * 32 + lq * 8]);
    #pragma unroll
    for (int g = 0; g < 4; ++g) {
      cxA[g] = __builtin_amdgcn_mfma_f32_16x16x32_f16(wb[g][kf], aA, cxA[g], 0, 0, 0);
      cxB[g] = __builtin_amdgcn_mfma_f32_16x16x32_f16(wb[g][kf], aB, cxB[g], 0, 0, 0);
    }
  }
  #pragma unroll
  for (int g = 0; g < 4; ++g) {
    int tile = w + 8 * g;
    #pragma unroll
    for (int kf = 0; kf < 4; ++kf)
      wb[g][kf] = *(const f16x8*)(whb + ((size_t)(tile * 4 + kf) * 64 + l) * 8);
  }

  // z_B^0 (for step 0), c-state init (c0 = att_proj)
  f32x4 zB[4] = {cxB[0], cxB[1], cxB[2], cxB[3]};
  #pragma unroll
  for (int kf = 0; kf < 4; ++kf) {
    f16x8 aB = *(const f16x8*)(&hB[lr][kf * 32 + lq * 8]);
    #pragma unroll
    for (int g = 0; g < 4; ++g)
      zB[g] = __builtin_amdgcn_mfma_f32_16x16x32_f16(wb[g][kf], aB, zB[g], 0, 0, 0);
  }
  float cstA[4], cstB[4];
  #pragma unroll
  for (int r = 0; r < 4; ++r) {
    cstA[r] = (float)hA[lr][j0 + r];
    cstB[r] = (float)hB[lr][j0 + r];
  }
  __syncthreads();  // prologue hB reads done before iter0 gates_B writes

  for (int t = 0; t < T_STEPS; ++t) {
    // ---- phase 1: MFMA_A (z_A^t) || gates_B (consume zB = z_B^t) ----
    f32x4 zA[4] = {cxA[0], cxA[1], cxA[2], cxA[3]};
    #pragma unroll
    for (int kf = 0; kf < 4; ++kf) {
      f16x8 a = *(const f16x8*)(&hA[lr][kf * 32 + lq * 8]);
      #pragma unroll
      for (int g = 0; g < 4; ++g)
        zA[g] = __builtin_amdgcn_mfma_f32_16x16x32_f16(wb[g][kf], a, zA[g], 0, 0, 0);
    }
    if (w6log && t > 0) logitS[t - 1][16 + lr] = zB[0][0];
    GATES(zB, cstB, hB)
    if (sduty && t + 1 < T_STEPS)
      hB[lr][100 + (lq - 1)] = sdvS[t + 1][16 + lr][lq - 1];
    __syncthreads();

    // ---- phase 2: MFMA_B (z_B^{t+1}) || gates_A (consume zA = z_A^t) ----
    if (w6log && t > 0) logitS[t - 1][lr] = zA[0][0];
    #pragma unroll
    for (int g = 0; g < 4; ++g) zB[g] = cxB[g];
    #pragma unroll
    for (int kf = 0; kf < 4; ++kf) {
      f16x8 a = *(const f16x8*)(&hB[lr][kf * 32 + lq * 8]);
      #pragma unroll
      for (int g = 0; g < 4; ++g)
        zB[g] = __builtin_amdgcn_mfma_f32_16x16x32_f16(wb[g][kf], a, zB[g], 0, 0, 0);
    }
    GATES(zA, cstA, hA)
    if (sduty && t + 1 < T_STEPS)
      hA[lr][100 + (lq - 1)] = sdvS[t + 1][lr][lq - 1];
    __syncthreads();
  }

  // final logits (t = T-1): B straight from zB regs; A needs 4 MFMA on tile 6
  if (w6log) logitS[T_STEPS - 1][16 + lr] = zB[0][0];
  if (w == 6) {
    f32x4 zL = {0.f, 0.f, 0.f, 0.f};
    #pragma unroll
    for (int kf = 0; kf < 4; ++kf) {
      f16x8 a = *(const f16x8*)(&hA[lr][kf * 32 + lq * 8]);
      zL = __builtin_amdgcn_mfma_f32_16x16x32_f16(wb[0][kf], a, zL, 0, 0, 0);
    }
    if (lq == 1) logitS[T_STEPS - 1][lr] = zL[0];
  }
  __syncthreads();

  // ---- tail: per-batch ego/IDM chain (32 batches), operands in LDS ----
  if (tid < 32) {
    int b = b0g + tid;
    const float* P = idm_params + (size_t)b * 5;
    float des_v = P[0], des_tg = P[1], min_jx = P[2], max_a = P[3];
    float inv2s = 0.5f / sqrtf(max_a * P[4]);
    float inv_dv = rcpf(des_v);
    float ego_v = idm_s[(size_t)b * 320 + 0];
    float ego_x = idm_s[(size_t)b * 320 + 3];
    float attb = att_b[0];
    float act = 0.f;
    #pragma unroll 4
    for (int t = 0; t < T_STEPS; ++t) {
      float2 s01 = *(const float2*)&sS[tid][t][0];
      float2 s23 = *(const float2*)&sS[tid][t][2];
      float2 s45 = *(const float2*)&sS[tid][t][4];
      float nf = nS[0][t][tid], nm = nS[1][t][tid];
      float lg = attb + logitS[t][tid];
      ego_v += act * 0.1f;
      ego_x += ego_v * 0.1f + act * 0.005f;
      float af_, am_;
      {
        float dx = fminf(fmaxf(s23.x - ego_x, 0.5f), 1000.f);
        float dg = min_jx + fmaxf(0.f, des_tg * ego_v + ego_v * (ego_v - s01.x) * inv2s);
        float r = ego_v * inv_dv; float r2 = r * r; float q = dg * rcpf(dx);
        af_ = fminf(fmaxf(max_a * (1.f - r2 * r2 - q * q), -3.f), 3.f);
      }
      {
        float dx = fminf(fmaxf(s23.y - ego_x, 0.5f), 1000.f);
        float dg = min_jx + fmaxf(0.f, des_tg * ego_v + ego_v * (ego_v - s01.y) * inv2s);
        float r = ego_v * inv_dv; float r2 = r * r; float q = dg * rcpf(dx);
        am_ = fminf(fmaxf(max_a * (1.f - r2 * r2 - q * q), -3.f), 3.f);
      }
      float ef2 = s45.x * af_ + (1.f - s45.x) * nf;
      float em2 = s45.y * am_ + (1.f - s45.y) * nm;
      float att = sigf(5.f * lg);
      act = (1.f - att) * ef2 + att * em2;
      accS[0][tid][t] = act;
      accS[1][tid][t] = att;
    }
  }
  __syncthreads();

  // coalesced output store: 1280 floats per output (320 f32x4)
  if (tid < 320) {
    f32x4 va = ((const f32x4*)&accS[0][0][0])[tid];
    f32x4 vt = ((const f32x4*)&accS[1][0][0])[tid];
    *(f32x4*)(out + (size_t)b0g * T_STEPS + tid * 4) = va;
    *(f32x4*)(out + (size_t)B_TOT * T_STEPS + (size_t)b0g * T_STEPS + tid * 4) = vt;
  }
}

extern "C" void kernel_launch(void* const* d_in, const int* in_sizes, int n_in,
                              void* d_out, int out_size, void* d_ws, size_t ws_size,
                              hipStream_t stream) {
  const float* z_att      = (const float*)d_in[0];
  const float* idm_params = (const float*)d_in[2];
  const float* idm_s      = (const float*)d_in[3];
  const float* sdv_acts   = (const float*)d_in[4];
  const float* linear_W   = (const float*)d_in[5];
  const float* linear_b   = (const float*)d_in[6];
  const float* lstm_Wx    = (const float*)d_in[7];
  const float* lstm_Wh    = (const float*)d_in[8];
  const float* lstm_b     = (const float*)d_in[9];
  const float* att_W      = (const float*)d_in[10];
  const float* att_b      = (const float*)d_in[11];
  const float* noise_f    = (const float*)d_in[12];
  const float* noise_m    = (const float*)d_in[13];
  float* out = (float*)d_out;

  f16*   whb = (f16*)d_ws;
  f16*   wxb = (f16*)((char*)d_ws + 131072);
  float* bp  = (float*)((char*)d_ws + 262144);

  idm_prep<<<256, 256, 0, stream>>>(lstm_Wx, lstm_Wh, lstm_b, att_W, whb, wxb, bp);
  idm_main<<<B_TOT / 32, 448, 0, stream>>>(z_att, linear_W, linear_b, sdv_acts,
                                           whb, wxb, bp,
                                           idm_params, idm_s, att_b,
                                           noise_f, noise_m, out);
}